// Round 6
// baseline (101.789 us; speedup 1.0000x reference)
//
#include <hip/hip_runtime.h>

#define IMG 8
#define LH 150
#define LQ 10
#define KITER 10   // 9 scan steps + final conv
#define ROW (IMG * IMG + 2)   // 66 floats per batch row

// ds_bpermute with precomputed BYTE address (hoists the <<2 out of hot loops).
// Must execute at full-wave convergence (inactive source lane => garbage).
__device__ __forceinline__ float bperm(int byte_addr, float v) {
    return __builtin_bit_cast(float,
        __builtin_amdgcn_ds_bpermute(byte_addr, __builtin_bit_cast(int, v)));
}

__device__ __forceinline__ float max10(const float q[LQ]) {
    const float g0 = fmaxf(fmaxf(q[0], q[1]), q[2]);
    const float g1 = fmaxf(fmaxf(q[3], q[4]), q[5]);
    const float g2 = fmaxf(fmaxf(q[6], q[7]), q[8]);
    return fmaxf(fmaxf(g0, g1), fmaxf(g2, q[9]));
}

// ---------------------------------------------------------------------------
// Pre-kernel: collapse h/r convs (exact — no nonlinearity between h and r).
//   ws[t] = sum_c Wr[c] * Wh[c, t]  (t=0..8),  ws[9] = sum_c Wr[c] * bh[c]
// ---------------------------------------------------------------------------
__global__ void weff_kernel(const float* __restrict__ Wh,
                            const float* __restrict__ bh,
                            const float* __restrict__ Wr,
                            float* __restrict__ ws) {
    const int wv = threadIdx.x >> 6;   // 0..9 (wave-uniform)
    const int lane = threadIdx.x & 63;
    float partial = 0.f;
    for (int c = lane; c < LH; c += 64) {
        const float wr = Wr[c];
        partial += wr * ((wv < 9) ? Wh[c * 9 + wv] : bh[c]);
    }
    #pragma unroll
    for (int off = 32; off > 0; off >>= 1)
        partial += __shfl_xor(partial, off);   // full wave active
    if (lane == 0) ws[wv] = partial;
}

// ---------------------------------------------------------------------------
// Main kernel: one wave = TWO batch items (independent chains for ILP);
// lane = pixel (y=lane>>3, x=lane&7). All shuffles at full-wave convergence;
// zero-pad via mask-mul after shuffle. Channel-major value iteration with
// running max (small live set); final iteration peeled and fused with the
// sel-lane broadcast so q[] is never fully materialized.
// __launch_bounds__(256,2): allow up to 256 arch VGPRs — the round-5 kernel
// was silently spilling to AGPRs at VGPR_Count=36 (live set >= 58).
// ---------------------------------------------------------------------------
__global__ __launch_bounds__(256, 2) void vin_kernel(
    const float* __restrict__ S,
    const float* __restrict__ Wq,
    const float* __restrict__ w,
    const float* __restrict__ Wfc,
    const float* __restrict__ ws,
    float* __restrict__ out,
    int B) {
    const int wave = threadIdx.x >> 6;
    const int lane = threadIdx.x & 63;
    const long b0 = (long)(blockIdx.x * 4 + wave) * 2;   // items b0, b0+1
    if (b0 >= B) return;                                  // wave-uniform

    const int y = lane >> 3, x = lane & 7;

    // 3x3 neighbor byte-addresses + zero-pad masks (shared by both items).
    int   addr[9];
    float msk[9];
    #pragma unroll
    for (int t = 0; t < 9; ++t) {
        const int dy = t / 3 - 1, dx = t % 3 - 1;
        const int ny = y + dy, nx = x + dx;
        const bool v = ((unsigned)ny < 8u) && ((unsigned)nx < 8u);
        addr[t] = (v ? (ny * 8 + nx) : 0) << 2;
        msk[t]  = v ? 1.f : 0.f;
    }

    const float* S0 = S + b0 * ROW;
    const float X0 = S0[lane];
    const float X1 = S0[ROW + lane];
    // (s1,s2) at row offsets 64,65 of each item's ROW=66 stride.
    const int sel0 = ((int)S0[IMG * IMG] * 8 + (int)S0[IMG * IMG + 1]) << 2;
    const int sel1 = ((int)S0[ROW + IMG * IMG] * 8 + (int)S0[ROW + IMG * IMG + 1]) << 2;

    // r = conv(X, Weff, pad=1) + beff  (mask folded into per-lane Weff copy)
    float r0 = ws[9], r1 = ws[9];
    #pragma unroll
    for (int t = 0; t < 9; ++t) {
        const float wm = ws[t] * msk[t];
        r0 = fmaf(wm, bperm(addr[t], X0), r0);
        r1 = fmaf(wm, bperm(addr[t], X1), r1);
    }

    // qr[o] = conv(r, Wq, pad=1)  — loop-invariant across the value iteration.
    float qr0[LQ], qr1[LQ];
    #pragma unroll
    for (int t = 0; t < 9; ++t) {
        const float a0 = bperm(addr[t], r0) * msk[t];
        const float a1 = bperm(addr[t], r1) * msk[t];
        #pragma unroll
        for (int o = 0; o < LQ; ++o) {
            const float wq = Wq[o * 9 + t];        // wave-uniform (SGPR)
            if (t == 0) { qr0[o] = a0 * wq; qr1[o] = a1 * wq; }
            else        { qr0[o] = fmaf(a0, wq, qr0[o]);
                          qr1[o] = fmaf(a1, wq, qr1[o]); }
        }
    }

    float v0 = max10(qr0), v1 = max10(qr1);

    // 9 scan steps: channel-major, running max — only acc/m live per item.
    for (int k = 0; k < KITER - 1; ++k) {
        float vn0[9], vn1[9];
        #pragma unroll
        for (int t = 0; t < 9; ++t) {
            vn0[t] = bperm(addr[t], v0) * msk[t];
            vn1[t] = bperm(addr[t], v1) * msk[t];
        }
        float m0, m1;
        #pragma unroll
        for (int o = 0; o < LQ; ++o) {
            float acc0 = qr0[o], acc1 = qr1[o];
            #pragma unroll
            for (int t = 0; t < 9; ++t) {
                const float wt = w[o * 9 + t];     // wave-uniform (SGPR)
                acc0 = fmaf(vn0[t], wt, acc0);
                acc1 = fmaf(vn1[t], wt, acc1);
            }
            if (o == 0) { m0 = acc0; m1 = acc1; }
            else        { m0 = fmaxf(m0, acc0); m1 = fmaxf(m1, acc1); }
        }
        v0 = m0; v1 = m1;
    }

    // Final conv, fused with the sel-lane broadcast (q[] never materialized).
    float qs0[LQ], qs1[LQ];
    {
        float vn0[9], vn1[9];
        #pragma unroll
        for (int t = 0; t < 9; ++t) {
            vn0[t] = bperm(addr[t], v0) * msk[t];
            vn1[t] = bperm(addr[t], v1) * msk[t];
        }
        #pragma unroll
        for (int o = 0; o < LQ; ++o) {
            float acc0 = qr0[o], acc1 = qr1[o];
            #pragma unroll
            for (int t = 0; t < 9; ++t) {
                const float wt = w[o * 9 + t];
                acc0 = fmaf(vn0[t], wt, acc0);
                acc1 = fmaf(vn1[t], wt, acc1);
            }
            qs0[o] = bperm(sel0, acc0);            // full convergence
            qs1[o] = bperm(sel1, acc1);
        }
    }

    // Lanes 0..7 emit item b0's logits, lanes 8..15 item b0+1's.
    if (lane < 16) {
        const int row = lane & 7;
        float acc = 0.f;
        #pragma unroll
        for (int o = 0; o < LQ; ++o)
            acc = fmaf((lane < 8) ? qs0[o] : qs1[o], Wfc[row * LQ + o], acc);
        out[b0 * 8 + lane] = acc;
    }
}

extern "C" void kernel_launch(void* const* d_in, const int* in_sizes, int n_in,
                              void* d_out, int out_size, void* d_ws, size_t ws_size,
                              hipStream_t stream) {
    const float* S   = (const float*)d_in[0];
    const float* Wh  = (const float*)d_in[1];
    const float* bh  = (const float*)d_in[2];
    const float* Wr  = (const float*)d_in[3];
    const float* Wq  = (const float*)d_in[4];
    const float* w   = (const float*)d_in[5];
    const float* Wfc = (const float*)d_in[6];
    float* out = (float*)d_out;
    float* ws  = (float*)d_ws;

    const int B = in_sizes[0] / ROW;

    weff_kernel<<<1, 640, 0, stream>>>(Wh, bh, Wr, ws);

    // 4 waves/block, 2 items/wave => 8 items per block.
    const int grid = (B + 7) / 8;
    vin_kernel<<<grid, 256, 0, stream>>>(S, Wq, w, Wfc, ws, out, B);
}

// Round 7
// 95.769 us; speedup vs baseline: 1.0629x; 1.0629x over previous
//
#include <hip/hip_runtime.h>

#define IMG 8
#define LH 150
#define LQ 10
#define KITER 10   // 9 scan steps + final conv
#define ROW (IMG * IMG + 2)   // 66 floats per batch row

// ds_bpermute with precomputed BYTE address. Must execute at full-wave
// convergence (inactive source lane => garbage).
__device__ __forceinline__ float bperm(int byte_addr, float v) {
    return __builtin_bit_cast(float,
        __builtin_amdgcn_ds_bpermute(byte_addr, __builtin_bit_cast(int, v)));
}

__device__ __forceinline__ float max10(const float q[LQ]) {
    const float g0 = fmaxf(fmaxf(q[0], q[1]), q[2]);
    const float g1 = fmaxf(fmaxf(q[3], q[4]), q[5]);
    const float g2 = fmaxf(fmaxf(q[6], q[7]), q[8]);
    return fmaxf(fmaxf(g0, g1), fmaxf(g2, q[9]));
}

// ---------------------------------------------------------------------------
// Pre-kernel: collapse h/r convs (exact — no nonlinearity between h and r).
//   ws[t] = sum_c Wr[c] * Wh[c, t]  (t=0..8),  ws[9] = sum_c Wr[c] * bh[c]
// ---------------------------------------------------------------------------
__global__ void weff_kernel(const float* __restrict__ Wh,
                            const float* __restrict__ bh,
                            const float* __restrict__ Wr,
                            float* __restrict__ ws) {
    const int wv = threadIdx.x >> 6;   // 0..9 (wave-uniform)
    const int lane = threadIdx.x & 63;
    float partial = 0.f;
    for (int c = lane; c < LH; c += 64) {
        const float wr = Wr[c];
        partial += wr * ((wv < 9) ? Wh[c * 9 + wv] : bh[c]);
    }
    #pragma unroll
    for (int off = 32; off > 0; off >>= 1)
        partial += __shfl_xor(partial, off);   // full wave active
    if (lane == 0) ws[wv] = partial;
}

// ---------------------------------------------------------------------------
// Main kernel: one wave = TWO batch items; lane = pixel (y=lane>>3, x=lane&7).
// Key round-7 change: the 90 scan-conv weights live in per-lane VGPRs with
// the zero-pad mask pre-multiplied in (wreg[o][t] = w[o,t]*msk[t]), so the
// k-loop has NO s_loads (no SMEM/DS lgkmcnt entanglement) and NO mask-muls:
//   acc = fma(bperm_raw(v), wreg, acc)
// Invalid taps bperm from lane 0 (finite garbage) but hit a 0.0 weight —
// bitwise-identical to masking the value. All shuffles at full convergence.
// ---------------------------------------------------------------------------
__global__ __launch_bounds__(256, 2) void vin_kernel(
    const float* __restrict__ S,
    const float* __restrict__ Wq,
    const float* __restrict__ w,
    const float* __restrict__ Wfc,
    const float* __restrict__ ws,
    float* __restrict__ out,
    int B) {
    const int wave = threadIdx.x >> 6;
    const int lane = threadIdx.x & 63;
    const long b0 = (long)(blockIdx.x * 4 + wave) * 2;   // items b0, b0+1
    if (b0 >= B) return;                                  // wave-uniform

    const int y = lane >> 3, x = lane & 7;

    // 3x3 neighbor byte-addresses + zero-pad masks.
    int   addr[9];
    float msk[9];
    #pragma unroll
    for (int t = 0; t < 9; ++t) {
        const int dy = t / 3 - 1, dx = t % 3 - 1;
        const int ny = y + dy, nx = x + dx;
        const bool v = ((unsigned)ny < 8u) && ((unsigned)nx < 8u);
        addr[t] = (v ? (ny * 8 + nx) : 0) << 2;
        msk[t]  = v ? 1.f : 0.f;
    }

    // Per-lane masked scan-conv weights, resident in VGPRs for the k-loop.
    float wreg[LQ][9];
    #pragma unroll
    for (int o = 0; o < LQ; ++o)
        #pragma unroll
        for (int t = 0; t < 9; ++t)
            wreg[o][t] = w[o * 9 + t] * msk[t];   // exact (x1 or x0)

    const float* S0 = S + b0 * ROW;
    const float X0 = S0[lane];
    const float X1 = S0[ROW + lane];
    // (s1,s2) at row offsets 64,65 of each item's ROW=66 stride.
    const int sel0 = ((int)S0[IMG * IMG] * 8 + (int)S0[IMG * IMG + 1]) << 2;
    const int sel1 = ((int)S0[ROW + IMG * IMG] * 8 + (int)S0[ROW + IMG * IMG + 1]) << 2;

    // r = conv(X, Weff, pad=1) + beff  (mask folded into per-lane Weff copy)
    float r0 = ws[9], r1 = ws[9];
    #pragma unroll
    for (int t = 0; t < 9; ++t) {
        const float wm = ws[t] * msk[t];
        r0 = fmaf(wm, bperm(addr[t], X0), r0);
        r1 = fmaf(wm, bperm(addr[t], X1), r1);
    }

    // qr[o] = conv(r, Wq, pad=1)  — loop-invariant across the value iteration.
    // (one-shot: mask-on-value + uniform s_load weights is fine here)
    float qr0[LQ], qr1[LQ];
    #pragma unroll
    for (int t = 0; t < 9; ++t) {
        const float a0 = bperm(addr[t], r0) * msk[t];
        const float a1 = bperm(addr[t], r1) * msk[t];
        #pragma unroll
        for (int o = 0; o < LQ; ++o) {
            const float wq = Wq[o * 9 + t];        // wave-uniform (SGPR)
            if (t == 0) { qr0[o] = a0 * wq; qr1[o] = a1 * wq; }
            else        { qr0[o] = fmaf(a0, wq, qr0[o]);
                          qr1[o] = fmaf(a1, wq, qr1[o]); }
        }
    }

    float v0 = max10(qr0), v1 = max10(qr1);

    // 9 scan steps: bperm_raw -> fma(wreg) only; running max per channel.
    #pragma unroll
    for (int k = 0; k < KITER - 1; ++k) {
        float vn0[9], vn1[9];
        #pragma unroll
        for (int t = 0; t < 9; ++t) {
            vn0[t] = bperm(addr[t], v0);           // unmasked; wreg carries mask
            vn1[t] = bperm(addr[t], v1);
        }
        float m0, m1;
        #pragma unroll
        for (int o = 0; o < LQ; ++o) {
            float acc0 = qr0[o], acc1 = qr1[o];
            #pragma unroll
            for (int t = 0; t < 9; ++t) {
                acc0 = fmaf(vn0[t], wreg[o][t], acc0);
                acc1 = fmaf(vn1[t], wreg[o][t], acc1);
            }
            if (o == 0) { m0 = acc0; m1 = acc1; }
            else        { m0 = fmaxf(m0, acc0); m1 = fmaxf(m1, acc1); }
        }
        v0 = m0; v1 = m1;
    }

    // Final conv, fused with the sel-lane broadcast (q[] never materialized).
    float qs0[LQ], qs1[LQ];
    {
        float vn0[9], vn1[9];
        #pragma unroll
        for (int t = 0; t < 9; ++t) {
            vn0[t] = bperm(addr[t], v0);
            vn1[t] = bperm(addr[t], v1);
        }
        #pragma unroll
        for (int o = 0; o < LQ; ++o) {
            float acc0 = qr0[o], acc1 = qr1[o];
            #pragma unroll
            for (int t = 0; t < 9; ++t) {
                acc0 = fmaf(vn0[t], wreg[o][t], acc0);
                acc1 = fmaf(vn1[t], wreg[o][t], acc1);
            }
            qs0[o] = bperm(sel0, acc0);            // full convergence
            qs1[o] = bperm(sel1, acc1);
        }
    }

    // Lanes 0..7 emit item b0's logits, lanes 8..15 item b0+1's.
    if (lane < 16) {
        const int row = lane & 7;
        float acc = 0.f;
        #pragma unroll
        for (int o = 0; o < LQ; ++o)
            acc = fmaf((lane < 8) ? qs0[o] : qs1[o], Wfc[row * LQ + o], acc);
        out[b0 * 8 + lane] = acc;
    }
}

extern "C" void kernel_launch(void* const* d_in, const int* in_sizes, int n_in,
                              void* d_out, int out_size, void* d_ws, size_t ws_size,
                              hipStream_t stream) {
    const float* S   = (const float*)d_in[0];
    const float* Wh  = (const float*)d_in[1];
    const float* bh  = (const float*)d_in[2];
    const float* Wr  = (const float*)d_in[3];
    const float* Wq  = (const float*)d_in[4];
    const float* w   = (const float*)d_in[5];
    const float* Wfc = (const float*)d_in[6];
    float* out = (float*)d_out;
    float* ws  = (float*)d_ws;

    const int B = in_sizes[0] / ROW;

    weff_kernel<<<1, 640, 0, stream>>>(Wh, bh, Wr, ws);

    // 4 waves/block, 2 items/wave => 8 items per block.
    const int grid = (B + 7) / 8;
    vin_kernel<<<grid, 256, 0, stream>>>(S, Wq, w, Wfc, ws, out, B);
}